// Round 14
// baseline (683.487 us; speedup 1.0000x reference)
//
#include <hip/hip_runtime.h>
#include <hip/hip_bf16.h>
#include <math.h>

#define NEG_SLOPE 0.2f
#define LOG2E 1.4426950408889634f

using bf16x8 = __attribute__((ext_vector_type(8))) short;
using f32x4  = __attribute__((ext_vector_type(4))) float;
using u16x8  = __attribute__((ext_vector_type(8))) unsigned short;
using u16x4  = __attribute__((ext_vector_type(4))) unsigned short;

__device__ __forceinline__ float lrelu(float x) { return x > 0.f ? x : NEG_SLOPE * x; }
__device__ __forceinline__ float dot4(float4 a, float4 b) {
    return a.x * b.x + a.y * b.y + a.z * b.z + a.w * b.w;
}
__device__ __forceinline__ unsigned short f2b(float x) {
    union { float f; unsigned u; } v; v.f = x;
    unsigned r = v.u + 0x7fff + ((v.u >> 16) & 1);
    return (unsigned short)(r >> 16);
}
__device__ __forceinline__ float b2f(unsigned short b) {
    union { unsigned u; float f; } v; v.u = ((unsigned)b) << 16;
    return v.f;
}
__device__ __forceinline__ float4 load4b(const unsigned short* p) {
    u16x4 u = *reinterpret_cast<const u16x4*>(p);
    return make_float4(b2f(u[0]), b2f(u[1]), b2f(u[2]), b2f(u[3]));
}
__device__ __forceinline__ bf16x8 cvt8(float4 a0, float4 a1) {
    union { u16x8 u; bf16x8 b; } c;
    c.u[0] = f2b(a0.x); c.u[1] = f2b(a0.y); c.u[2] = f2b(a0.z); c.u[3] = f2b(a0.w);
    c.u[4] = f2b(a1.x); c.u[5] = f2b(a1.y); c.u[6] = f2b(a1.z); c.u[7] = f2b(a1.w);
    return c.b;
}

// ---------------------------------------------------------------------------
// Pack per-relation Wcat[128 x 528] into MFMA fragment-linear bf16:
//   cols 0-255 = W1 (pool), 256-511 = W2 (resid),
//   512-519 = wel[k][h], 520-527 = wer[k][h]  (score columns; wvec prescaled)
// ---------------------------------------------------------------------------
struct PackArgs {
    const float* W1[4];
    const float* W2[4];
    const float* wvA[4];
    const float* wvB[4];
    unsigned short* Bp[4];
};

__global__ __launch_bounds__(256)
void pack_b_k(PackArgs pa)
{
    const int r = blockIdx.y;
    const int nb = blockIdx.x;                 // 0..32
    const int ks = threadIdx.x >> 6;
    const int lane = threadIdx.x & 63;
    const int n = nb * 16 + (lane & 15);
    const int k0 = ks * 32 + (lane >> 4) * 8;
    u16x8 u;
    if (n < 512) {
        const float* Wsrc = (n < 256) ? (pa.W1[r] + n) : (pa.W2[r] + (n - 256));
        #pragma unroll
        for (int e = 0; e < 8; ++e) u[e] = f2b(Wsrc[(size_t)(k0 + e) * 256]);
    } else {
        const int h = (n - 512) & 7;
        const bool isEr = (n >= 520);
        const float* wv = isEr ? (pa.wvB[r] + h * 64 + 32) : (pa.wvA[r] + h * 64);
        const float* Wc = pa.W1[r] + h * 32;
        #pragma unroll
        for (int e = 0; e < 8; ++e) {
            const size_t k = (size_t)(k0 + e);
            float s = 0.f;
            #pragma unroll 8
            for (int d = 0; d < 32; ++d) s = fmaf(Wc[k * 256 + d], wv[d], s);
            u[e] = f2b(s);
        }
    }
    const size_t gid = (size_t)((nb * 4 + ks) * 64 + lane);
    *reinterpret_cast<u16x8*>(pa.Bp[r] + gid * 8) = u;
}

// ---------------------------------------------------------------------------
// Operand-swap MFMA GEMM, Bp staged through LDS in 32 KB phases (R13 frozen).
// ---------------------------------------------------------------------------
struct GemmArgs {
    const float* A[4];
    const unsigned short* Bp[4];
    const float* bres[4];
    unsigned short* pool[4];
    unsigned short* resid[4];    // resid[pair[r]] slot
    float* elOut[4];             // el[r]
    float* erOut[4];             // er[pair[r]]
};

__global__ __launch_bounds__(256)
void mfma_gemm_k(GemmArgs ga, int Nrows)
{
    __shared__ __align__(16) char smem[65536];
    unsigned short* slab = (unsigned short*)smem;        // 32 KB
    char* bounce = smem + 32768;                         // 32 KB
    const int rsel = blockIdx.y;
    const int t = threadIdx.x;
    const int wv = t >> 6, lane = t & 63;
    const int l15 = lane & 15, lg = lane >> 4;
    const int nloc = wv * 16 + l15;              // 0..63
    const int m0 = blockIdx.x * 64;
    const int node = m0 + nloc;
    const bool valid = node < Nrows;
    const int nc = valid ? node : (Nrows - 1);

    const float* __restrict__ A = ga.A[rsel];
    const unsigned short* __restrict__ Bp = ga.Bp[rsel];
    const float* __restrict__ bres = ga.bres[rsel];

    bf16x8 bfr[4];
    #pragma unroll
    for (int ks = 0; ks < 4; ++ks) {
        const float* p = A + (size_t)nc * 128 + ks * 32 + lg * 8;
        float4 a0 = *reinterpret_cast<const float4*>(p);
        float4 a1 = *reinterpret_cast<const float4*>(p + 4);
        bfr[ks] = cvt8(a0, a1);
    }

    const int swz = (nloc & 7) << 4;

    u16x8 sreg[8];
    #pragma unroll
    for (int j = 0; j < 8; ++j)
        sreg[j] = *reinterpret_cast<const u16x8*>(Bp + (size_t)(j * 256 + t) * 8);

    u16x8 snext;

    #pragma unroll
    for (int p = 0; p < 4; ++p) {
        #pragma unroll
        for (int j = 0; j < 8; ++j)
            *reinterpret_cast<u16x8*>(slab + (size_t)(j * 256 + t) * 8) = sreg[j];
        __syncthreads();
        if (p < 3) {
            const unsigned short* src = Bp + (size_t)(p + 1) * 16384;
            #pragma unroll
            for (int j = 0; j < 8; ++j)
                sreg[j] = *reinterpret_cast<const u16x8*>(src + (size_t)(j * 256 + t) * 8);
        } else {
            snext = *reinterpret_cast<const u16x8*>(Bp + (size_t)65536 + (size_t)t * 8);
        }
        const bool isPool = (p < 2);
        #pragma unroll
        for (int i = 0; i < 8; ++i) {
            const int ni = p * 8 + i;
            f32x4 acc = (f32x4){0.f, 0.f, 0.f, 0.f};
            #pragma unroll
            for (int ks = 0; ks < 4; ++ks) {
                bf16x8 wf = *reinterpret_cast<const bf16x8*>(
                    slab + (size_t)((i * 4 + ks) * 64 + lane) * 8);
                acc = __builtin_amdgcn_mfma_f32_16x16x32_bf16(wf, bfr[ks], acc, 0, 0, 0);
            }
            const int cni = isPool ? ni : (ni - 16);
            u16x4 o;
            if (isPool) {
                o[0] = f2b(acc[0]); o[1] = f2b(acc[1]);
                o[2] = f2b(acc[2]); o[3] = f2b(acc[3]);
            } else {
                float4 bv = *reinterpret_cast<const float4*>(bres + cni * 16 + lg * 4);
                o[0] = f2b(acc[0] + bv.x); o[1] = f2b(acc[1] + bv.y);
                o[2] = f2b(acc[2] + bv.z); o[3] = f2b(acc[3] + bv.w);
            }
            *reinterpret_cast<u16x4*>(bounce + nloc * 512 + ((cni * 32 + lg * 8) ^ swz)) = o;
        }
        __syncthreads();
        if (p == 1) {
            unsigned short* __restrict__ dst = ga.pool[rsel];
            #pragma unroll
            for (int i = 0; i < 8; ++i) {
                const int chunk = i * 256 + t;
                const int row = chunk >> 5;
                const int c16 = chunk & 31;
                const int byte = row * 512 + ((c16 * 16) ^ ((row & 7) << 4));
                u16x8 v = *reinterpret_cast<const u16x8*>(bounce + byte);
                if (m0 + row < Nrows)
                    *reinterpret_cast<u16x8*>(dst + (size_t)(m0 + row) * 256 + c16 * 8) = v;
            }
            __syncthreads();
        }
    }
    *reinterpret_cast<u16x8*>(slab + (size_t)t * 8) = snext;
    {
        unsigned short* __restrict__ dst = ga.resid[rsel];
        #pragma unroll
        for (int i = 0; i < 8; ++i) {
            const int chunk = i * 256 + t;
            const int row = chunk >> 5;
            const int c16 = chunk & 31;
            const int byte = row * 512 + ((c16 * 16) ^ ((row & 7) << 4));
            u16x8 v = *reinterpret_cast<const u16x8*>(bounce + byte);
            if (m0 + row < Nrows)
                *reinterpret_cast<u16x8*>(dst + (size_t)(m0 + row) * 256 + c16 * 8) = v;
        }
    }
    __syncthreads();
    {
        f32x4 acc = (f32x4){0.f, 0.f, 0.f, 0.f};
        #pragma unroll
        for (int ks = 0; ks < 4; ++ks) {
            bf16x8 wf = *reinterpret_cast<const bf16x8*>(
                slab + (size_t)(ks * 64 + lane) * 8);
            acc = __builtin_amdgcn_mfma_f32_16x16x32_bf16(wf, bfr[ks], acc, 0, 0, 0);
        }
        if (valid) {
            float4 v = make_float4(acc[0], acc[1], acc[2], acc[3]);
            if (lg < 2)
                *reinterpret_cast<float4*>(ga.elOut[rsel] + (size_t)node * 8 + lg * 4) = v;
            else
                *reinterpret_cast<float4*>(ga.erOut[rsel] + (size_t)node * 8 + (lg - 2) * 4) = v;
        }
    }
}

// ---------------------------------------------------------------------------
// CSR build (batched over 4 relations via blockIdx.y)
// ---------------------------------------------------------------------------
struct EdgePtrs {
    const int* src[4];
    const int* dst[4];
    int E[4];
    int csrOff[4];
};

__global__ __launch_bounds__(256)
void hist_k(EdgePtrs ep, int* __restrict__ counts4, int N)
{
    const int r = blockIdx.y;
    const int e = blockIdx.x * 256 + threadIdx.x;
    if (e < ep.E[r]) atomicAdd(counts4 + (size_t)r * N + ep.dst[r][e], 1);
}

__global__ __launch_bounds__(256)
void blksum_k(const int* __restrict__ counts4, int* __restrict__ blksum4, int N)
{
    const int r = blockIdx.y;
    const int* c = counts4 + (size_t)r * N;
    const int base = blockIdx.x * 1024 + threadIdx.x;
    int s = 0;
    #pragma unroll
    for (int i = 0; i < 4; ++i) { int idx = base + i * 256; if (idx < N) s += c[idx]; }
    __shared__ int sd[256];
    sd[threadIdx.x] = s; __syncthreads();
    for (int off = 128; off > 0; off >>= 1) {
        if (threadIdx.x < off) sd[threadIdx.x] += sd[threadIdx.x + off];
        __syncthreads();
    }
    if (threadIdx.x == 0) blksum4[r * 1024 + blockIdx.x] = sd[0];
}

__global__ __launch_bounds__(1024)
void scanblk_k(int* __restrict__ blksum4, int nbx)
{
    const int r = blockIdx.x;
    const int t = threadIdx.x;
    __shared__ int sd[1024];
    int v = (t < nbx) ? blksum4[r * 1024 + t] : 0;
    sd[t] = v; __syncthreads();
    for (int off = 1; off < 1024; off <<= 1) {
        int u = (t >= off) ? sd[t - off] : 0;
        __syncthreads();
        sd[t] += u;
        __syncthreads();
    }
    if (t < nbx) blksum4[r * 1024 + t] = sd[t] - v;
}

__global__ __launch_bounds__(256)
void cursor_k(const int* __restrict__ counts4, const int* __restrict__ blkoff4,
              int* __restrict__ cursor4, int N)
{
    const int r = blockIdx.y;
    const int* c = counts4 + (size_t)r * N;
    int* cur = cursor4 + (size_t)r * N;
    const int t = threadIdx.x;
    const int base = blockIdx.x * 1024 + t * 4;
    const int c0 = (base + 0 < N) ? c[base + 0] : 0;
    const int c1 = (base + 1 < N) ? c[base + 1] : 0;
    const int c2 = (base + 2 < N) ? c[base + 2] : 0;
    const int c3 = (base + 3 < N) ? c[base + 3] : 0;
    const int tsum = c0 + c1 + c2 + c3;
    __shared__ int sd[256];
    sd[t] = tsum; __syncthreads();
    for (int off = 1; off < 256; off <<= 1) {
        int u = (t >= off) ? sd[t - off] : 0;
        __syncthreads();
        sd[t] += u;
        __syncthreads();
    }
    int excl = sd[t] - tsum + blkoff4[r * 1024 + blockIdx.x];
    if (base + 0 < N) cur[base + 0] = excl;
    if (base + 1 < N) cur[base + 1] = excl + c0;
    if (base + 2 < N) cur[base + 2] = excl + c0 + c1;
    if (base + 3 < N) cur[base + 3] = excl + c0 + c1 + c2;
}

__global__ __launch_bounds__(256)
void scatter_k(EdgePtrs ep, int* __restrict__ cursor4, int* __restrict__ csr_src, int N)
{
    const int r = blockIdx.y;
    const int e = blockIdx.x * 256 + threadIdx.x;
    if (e < ep.E[r]) {
        const int d = ep.dst[r][e];
        const int pos = atomicAdd(cursor4 + (size_t)r * N + d, 1);
        csr_src[ep.csrOff[r] + pos] = ep.src[r][e];
    }
}

// ---------------------------------------------------------------------------
// Fused per-node kernel. One wave per node, 4 elems/lane.
// CROSS-RELATION interleave: each phase issues 4-edge chunks for ALL 4
// relations (invalid slots masked to ex=0), collapsing 4 serial latency
// bursts into ceil(maxdeg/4) phases with ~16 loads in flight.
// Unsigned 32-bit offsets in the hot loop (no 64-bit v_mad chains).
// ---------------------------------------------------------------------------
struct NodeArgs {
    const int* csr[4];
    const int* cursor[4];
    const int* counts[4];
    const float* el[4];
    const float* er[4];
    const unsigned short* pool[4];
    const unsigned short* resid[4];
};

__global__ __launch_bounds__(256)
void node_k(NodeArgs na,
            const float* __restrict__ attn_ui, const float* __restrict__ attn_ii,
            const float* __restrict__ attn_iir,
            const float* __restrict__ a_user, const float* __restrict__ a_item,
            float* __restrict__ out, int Nrows)
{
    const int lane = threadIdx.x & 63;
    const int n = blockIdx.x * 4 + (threadIdx.x >> 6);
    if (n >= Nrows) return;
    const unsigned k = (unsigned)(lane >> 3);
    const unsigned c4 = (unsigned)(lane * 4);

    int deg[4], start[4];
    float erk[4];
    #pragma unroll
    for (int r = 0; r < 4; ++r) {
        deg[r] = na.counts[r][n];
        const int endv = na.cursor[r][n];
        start[r] = (deg[r] > 0) ? (endv - deg[r]) : 0;
        erk[r] = na.er[r][(size_t)n * 8 + k];
    }
    int maxd = deg[0];
    maxd = deg[1] > maxd ? deg[1] : maxd;
    maxd = deg[2] > maxd ? deg[2] : maxd;
    maxd = deg[3] > maxd ? deg[3] : maxd;

    const float si = 1.f / (1.f + __expf(-a_item[0])), osi = 1.f - si;
    const float su = 1.f / (1.f + __expf(-a_user[0])), osu = 1.f - su;

    float s[4] = {0.f, 0.f, 0.f, 0.f};
    float4 acc[4];
    #pragma unroll
    for (int r = 0; r < 4; ++r) acc[r] = make_float4(0.f, 0.f, 0.f, 0.f);

    for (int base = 0; base < maxd; base += 4) {
        int sidx[4][4];
        #pragma unroll
        for (int r = 0; r < 4; ++r) {
            #pragma unroll
            for (int u = 0; u < 4; ++u) {
                const int idx = base + u;
                const int cc = (idx < deg[r]) ? idx : 0;
                sidx[r][u] = na.csr[r][start[r] + cc];
            }
        }
        float ex[4][4];
        #pragma unroll
        for (int r = 0; r < 4; ++r) {
            #pragma unroll
            for (int u = 0; u < 4; ++u) {
                const float x = na.el[r][(unsigned)sidx[r][u] * 8u + k] + erk[r];
                const float e = __builtin_amdgcn_exp2f(fmaxf(x, NEG_SLOPE * x));
                ex[r][u] = (base + u < deg[r]) ? e : 0.f;
            }
        }
        #pragma unroll
        for (int r = 0; r < 4; ++r) {
            float4 pv[4];
            #pragma unroll
            for (int u = 0; u < 4; ++u)
                pv[u] = load4b(na.pool[r] + (unsigned)sidx[r][u] * 256u + c4);
            #pragma unroll
            for (int u = 0; u < 4; ++u) {
                s[r] += ex[r][u];
                acc[r].x = fmaf(pv[u].x, ex[r][u], acc[r].x);
                acc[r].y = fmaf(pv[u].y, ex[r][u], acc[r].y);
                acc[r].z = fmaf(pv[u].z, ex[r][u], acc[r].z);
                acc[r].w = fmaf(pv[u].w, ex[r][u], acc[r].w);
            }
        }
    }

    float4 fr[4];
    #pragma unroll
    for (int r = 0; r < 4; ++r) {
        const float inv = (deg[r] > 0) ? 1.f / s[r] : 0.f;
        float4 R = load4b(na.resid[r] + (unsigned)n * 256u + c4);
        const float sg = (r == 1) ? su : si;
        const float og = (r == 1) ? osu : osi;
        fr[r].x = sg * fmaxf(acc[r].x * inv, 0.f) + og * R.x;
        fr[r].y = sg * fmaxf(acc[r].y * inv, 0.f) + og * R.y;
        fr[r].z = sg * fmaxf(acc[r].z * inv, 0.f) + og * R.z;
        fr[r].w = sg * fmaxf(acc[r].w * inv, 0.f) + og * R.w;
    }

    const float4 f0 = fr[0], f1 = fr[2], f2 = fr[3], fiu = fr[1];
    float4 w0 = *reinterpret_cast<const float4*>(attn_ui  + lane * 4);
    float4 w1 = *reinterpret_cast<const float4*>(attn_ii  + lane * 4);
    float4 w2 = *reinterpret_cast<const float4*>(attn_iir + lane * 4);

    float p[3][3];
    p[0][0] = dot4(w0, f0); p[0][1] = dot4(w0, f1); p[0][2] = dot4(w0, f2);
    p[1][0] = dot4(w1, f0); p[1][1] = dot4(w1, f1); p[1][2] = dot4(w1, f2);
    p[2][0] = dot4(w2, f0); p[2][1] = dot4(w2, f1); p[2][2] = dot4(w2, f2);
    #pragma unroll
    for (int x = 0; x < 3; ++x)
        #pragma unroll
        for (int r = 0; r < 3; ++r)
            #pragma unroll
            for (int m = 1; m < 8; m <<= 1)
                p[x][r] += __shfl_xor(p[x][r], m, 64);

    const size_t NK = (size_t)Nrows * 256;
    const size_t o = (size_t)n * 256 + lane * 4;
    const size_t xoff[3] = {0, 2 * NK, 3 * NK};
    #pragma unroll
    for (int x = 0; x < 3; ++x) {
        float a0 = lrelu(p[x][0]), a1 = lrelu(p[x][1]), a2 = lrelu(p[x][2]);
        float mx = fmaxf(a0, fmaxf(a1, a2));
        float e0 = __expf(a0 - mx), e1 = __expf(a1 - mx), e2 = __expf(a2 - mx);
        float inv = 1.f / (e0 + e1 + e2);
        e0 *= inv; e1 *= inv; e2 *= inv;
        float4 rr;
        rr.x = e0 * f0.x + e1 * f1.x + e2 * f2.x;
        rr.y = e0 * f0.y + e1 * f1.y + e2 * f2.y;
        rr.z = e0 * f0.z + e1 * f1.z + e2 * f2.z;
        rr.w = e0 * f0.w + e1 * f1.w + e2 * f2.w;
        *reinterpret_cast<float4*>(out + xoff[x] + o) = rr;
    }
    *reinterpret_cast<float4*>(out + NK + o) = fiu;
}

// ---------------------------------------------------------------------------
// Relation-level tiny matvecs. wvec pre-scaled by LOG2E; ro NOT scaled.
// ---------------------------------------------------------------------------
struct RelPtrs {
    const float* rf[4];
    const float* Wrel[4];
    const float* Wupd[4];
    const float* bupd[4];
};

__global__ __launch_bounds__(512)
void rel_k(RelPtrs P, float* __restrict__ wvec, float* __restrict__ ro)
{
    const int r = blockIdx.x;
    const int t = threadIdx.x;
    __shared__ float rfs[64];
    if (t < 64) rfs[t] = P.rf[r][t];
    __syncthreads();
    {
        const float* Wc = P.Wrel[r];
        float acc = 0.f;
        #pragma unroll 8
        for (int i = 0; i < 64; ++i) acc = fmaf(rfs[i], Wc[(size_t)i * 512 + t], acc);
        wvec[(size_t)r * 512 + t] = acc * LOG2E;
    }
    if (t < 256) {
        const float* Wc = P.Wupd[r];
        float acc = P.bupd[r][t];
        #pragma unroll 8
        for (int i = 0; i < 64; ++i) acc = fmaf(rfs[i], Wc[(size_t)i * 256 + t], acc);
        ro[(size_t)r * 256 + t] = acc;
    }
}

// ---------------------------------------------------------------------------
extern "C" void kernel_launch(void* const* d_in, const int* in_sizes, int n_in,
                              void* d_out, int out_size, void* d_ws, size_t ws_size,
                              hipStream_t stream)
{
    (void)n_in; (void)out_size; (void)ws_size;
    const float* feat_ui  = (const float*)d_in[0];
    const float* feat_iu  = (const float*)d_in[1];
    const float* feat_ii  = (const float*)d_in[2];
    const float* feat_iir = (const float*)d_in[3];
    const float* W_user   = (const float*)d_in[8];
    const float* W_item   = (const float*)d_in[9];
    const float* Wres_user = (const float*)d_in[18];
    const float* bres_user = (const float*)d_in[19];
    const float* Wres_item = (const float*)d_in[20];
    const float* bres_item = (const float*)d_in[21];
    const float* a_user = (const float*)d_in[22];
    const float* a_item = (const float*)d_in[23];
    const int N = in_sizes[0] / 128;
    const int Es[4] = {in_sizes[32], in_sizes[34], in_sizes[36], in_sizes[38]};
    int maxE = 0;
    for (int r = 0; r < 4; ++r) maxE = Es[r] > maxE ? Es[r] : maxE;

    const size_t NP = (size_t)N * 256;
    const size_t N8 = (size_t)N * 8;
    const size_t BPSZ = 33 * 4 * 64 * 8;              // u16 per relation pack

    unsigned short* us = (unsigned short*)d_ws;
    unsigned short* pool[4];
    unsigned short* resid[4];
    for (int r = 0; r < 4; ++r) pool[r]  = us + (size_t)r * NP;
    for (int r = 0; r < 4; ++r) resid[r] = us + (size_t)(4 + r) * NP;
    unsigned short* BpArr[4];
    for (int r = 0; r < 4; ++r) BpArr[r] = us + 8 * NP + (size_t)r * BPSZ;
    float* fl = (float*)(us + 8 * NP + 4 * BPSZ);
    float *el[4], *er[4];
    for (int r = 0; r < 4; ++r) { el[r] = fl + (size_t)(2 * r) * N8; er[r] = fl + (size_t)(2 * r + 1) * N8; }
    float* wvec = fl + 8 * N8;                        // 4 x 512
    int* counts4 = (int*)(wvec + 4 * 512);
    int* cursor4 = counts4 + 4 * (size_t)N;
    int* blksum4 = cursor4 + 4 * (size_t)N;
    int* csr_src = blksum4 + 4 * 1024;
    float* out = (float*)d_out;

    EdgePtrs ep;
    {
        int off = 0;
        const int si[4] = {32, 34, 36, 38};
        for (int r = 0; r < 4; ++r) {
            ep.src[r] = (const int*)d_in[si[r]];
            ep.dst[r] = (const int*)d_in[si[r] + 1];
            ep.E[r] = Es[r];
            ep.csrOff[r] = off;
            off += Es[r];
        }
    }

    (void)hipMemsetAsync(counts4, 0, 4 * (size_t)N * sizeof(int), stream);

    RelPtrs rp;
    rp.rf[0]   = (const float*)d_in[4];  rp.rf[1]   = (const float*)d_in[5];
    rp.rf[2]   = (const float*)d_in[6];  rp.rf[3]   = (const float*)d_in[7];
    rp.Wrel[0] = (const float*)d_in[10]; rp.Wrel[1] = (const float*)d_in[11];
    rp.Wrel[2] = (const float*)d_in[12]; rp.Wrel[3] = (const float*)d_in[13];
    rp.Wupd[0] = (const float*)d_in[24]; rp.Wupd[1] = (const float*)d_in[26];
    rp.Wupd[2] = (const float*)d_in[28]; rp.Wupd[3] = (const float*)d_in[30];
    rp.bupd[0] = (const float*)d_in[25]; rp.bupd[1] = (const float*)d_in[27];
    rp.bupd[2] = (const float*)d_in[29]; rp.bupd[3] = (const float*)d_in[31];
    rel_k<<<dim3(4), dim3(512), 0, stream>>>(rp, wvec, out + 4 * NP);

    // per-relation weight packs (needs wvec for the score columns)
    const int pair[4] = {1, 0, 3, 2};
    PackArgs pa;
    pa.W1[0] = W_user; pa.W2[0] = Wres_user;
    pa.W1[1] = W_item; pa.W2[1] = Wres_item;
    pa.W1[2] = W_item; pa.W2[2] = Wres_item;
    pa.W1[3] = W_item; pa.W2[3] = Wres_item;
    for (int r = 0; r < 4; ++r) {
        pa.wvA[r] = wvec + (size_t)r * 512;
        pa.wvB[r] = wvec + (size_t)pair[r] * 512;
        pa.Bp[r]  = BpArr[r];
    }
    pack_b_k<<<dim3(33, 4), 256, 0, stream>>>(pa);

    // CSR build
    const int geb = (maxE + 255) / 256;
    const int nbx = (N + 1023) / 1024;
    hist_k<<<dim3(geb, 4), 256, 0, stream>>>(ep, counts4, N);
    blksum_k<<<dim3(nbx, 4), 256, 0, stream>>>(counts4, blksum4, N);
    scanblk_k<<<dim3(4), 1024, 0, stream>>>(blksum4, nbx);
    cursor_k<<<dim3(nbx, 4), 256, 0, stream>>>(counts4, blksum4, cursor4, N);
    scatter_k<<<dim3(geb, 4), 256, 0, stream>>>(ep, cursor4, csr_src, N);

    // operand-swap fused GEMM (pool + resid + el/er), all 4 relations batched
    GemmArgs ga;
    ga.A[0] = feat_iu;  ga.bres[0] = bres_user;
    ga.A[1] = feat_ui;  ga.bres[1] = bres_item;
    ga.A[2] = feat_iir; ga.bres[2] = bres_item;
    ga.A[3] = feat_ii;  ga.bres[3] = bres_item;
    for (int r = 0; r < 4; ++r) {
        ga.Bp[r]    = BpArr[r];
        ga.pool[r]  = pool[r];
        ga.resid[r] = resid[pair[r]];
        ga.elOut[r] = el[r];
        ga.erOut[r] = er[pair[r]];
    }
    const int gb = (N + 63) / 64;
    mfma_gemm_k<<<dim3(gb, 4), 256, 0, stream>>>(ga, N);

    // fused aggregation + gated residual + cross-relation fusion
    NodeArgs na;
    for (int r = 0; r < 4; ++r) {
        na.csr[r]    = csr_src + ep.csrOff[r];
        na.cursor[r] = cursor4 + (size_t)r * N;
        na.counts[r] = counts4 + (size_t)r * N;
        na.el[r]     = el[r];
        na.er[r]     = er[r];
        na.pool[r]   = pool[r];
        na.resid[r]  = resid[r];
    }
    const int nb4 = (N + 3) / 4;
    node_k<<<nb4, 256, 0, stream>>>(na,
                                    (const float*)d_in[14], (const float*)d_in[16],
                                    (const float*)d_in[17],
                                    a_user, a_item, out, N);
}

// Round 15
// 572.112 us; speedup vs baseline: 1.1947x; 1.1947x over previous
//
#include <hip/hip_runtime.h>
#include <hip/hip_bf16.h>
#include <math.h>

#define NEG_SLOPE 0.2f
#define LOG2E 1.4426950408889634f

using bf16x8 = __attribute__((ext_vector_type(8))) short;
using f32x4  = __attribute__((ext_vector_type(4))) float;
using u16x8  = __attribute__((ext_vector_type(8))) unsigned short;
using u16x4  = __attribute__((ext_vector_type(4))) unsigned short;

__device__ __forceinline__ float lrelu(float x) { return x > 0.f ? x : NEG_SLOPE * x; }
__device__ __forceinline__ float dot4(float4 a, float4 b) {
    return a.x * b.x + a.y * b.y + a.z * b.z + a.w * b.w;
}
__device__ __forceinline__ unsigned short f2b(float x) {
    union { float f; unsigned u; } v; v.f = x;
    unsigned r = v.u + 0x7fff + ((v.u >> 16) & 1);
    return (unsigned short)(r >> 16);
}
__device__ __forceinline__ float b2f(unsigned short b) {
    union { unsigned u; float f; } v; v.u = ((unsigned)b) << 16;
    return v.f;
}
__device__ __forceinline__ float4 load4b(const unsigned short* p) {
    u16x4 u = *reinterpret_cast<const u16x4*>(p);
    return make_float4(b2f(u[0]), b2f(u[1]), b2f(u[2]), b2f(u[3]));
}
__device__ __forceinline__ bf16x8 cvt8(float4 a0, float4 a1) {
    union { u16x8 u; bf16x8 b; } c;
    c.u[0] = f2b(a0.x); c.u[1] = f2b(a0.y); c.u[2] = f2b(a0.z); c.u[3] = f2b(a0.w);
    c.u[4] = f2b(a1.x); c.u[5] = f2b(a1.y); c.u[6] = f2b(a1.z); c.u[7] = f2b(a1.w);
    return c.b;
}

// ---------------------------------------------------------------------------
// Pack per-relation Wcat[128 x 528] into MFMA fragment-linear bf16:
//   cols 0-255 = W1 (pool), 256-511 = W2 (resid),
//   512-519 = wel[k][h], 520-527 = wer[k][h]  (score columns; wvec prescaled)
// ---------------------------------------------------------------------------
struct PackArgs {
    const float* W1[4];
    const float* W2[4];
    const float* wvA[4];
    const float* wvB[4];
    unsigned short* Bp[4];
};

__global__ __launch_bounds__(256)
void pack_b_k(PackArgs pa)
{
    const int r = blockIdx.y;
    const int nb = blockIdx.x;                 // 0..32
    const int ks = threadIdx.x >> 6;
    const int lane = threadIdx.x & 63;
    const int n = nb * 16 + (lane & 15);
    const int k0 = ks * 32 + (lane >> 4) * 8;
    u16x8 u;
    if (n < 512) {
        const float* Wsrc = (n < 256) ? (pa.W1[r] + n) : (pa.W2[r] + (n - 256));
        #pragma unroll
        for (int e = 0; e < 8; ++e) u[e] = f2b(Wsrc[(size_t)(k0 + e) * 256]);
    } else {
        const int h = (n - 512) & 7;
        const bool isEr = (n >= 520);
        const float* wv = isEr ? (pa.wvB[r] + h * 64 + 32) : (pa.wvA[r] + h * 64);
        const float* Wc = pa.W1[r] + h * 32;
        #pragma unroll
        for (int e = 0; e < 8; ++e) {
            const size_t k = (size_t)(k0 + e);
            float s = 0.f;
            #pragma unroll 8
            for (int d = 0; d < 32; ++d) s = fmaf(Wc[k * 256 + d], wv[d], s);
            u[e] = f2b(s);
        }
    }
    const size_t gid = (size_t)((nb * 4 + ks) * 64 + lane);
    *reinterpret_cast<u16x8*>(pa.Bp[r] + gid * 8) = u;
}

// ---------------------------------------------------------------------------
// Operand-swap MFMA GEMM, Bp staged through LDS in 32 KB phases (R13 frozen).
// ---------------------------------------------------------------------------
struct GemmArgs {
    const float* A[4];
    const unsigned short* Bp[4];
    const float* bres[4];
    unsigned short* pool[4];
    unsigned short* resid[4];    // resid[pair[r]] slot
    float* elOut[4];             // el[r]
    float* erOut[4];             // er[pair[r]]
};

__global__ __launch_bounds__(256)
void mfma_gemm_k(GemmArgs ga, int Nrows)
{
    __shared__ __align__(16) char smem[65536];
    unsigned short* slab = (unsigned short*)smem;        // 32 KB
    char* bounce = smem + 32768;                         // 32 KB
    const int rsel = blockIdx.y;
    const int t = threadIdx.x;
    const int wv = t >> 6, lane = t & 63;
    const int l15 = lane & 15, lg = lane >> 4;
    const int nloc = wv * 16 + l15;              // 0..63
    const int m0 = blockIdx.x * 64;
    const int node = m0 + nloc;
    const bool valid = node < Nrows;
    const int nc = valid ? node : (Nrows - 1);

    const float* __restrict__ A = ga.A[rsel];
    const unsigned short* __restrict__ Bp = ga.Bp[rsel];
    const float* __restrict__ bres = ga.bres[rsel];

    bf16x8 bfr[4];
    #pragma unroll
    for (int ks = 0; ks < 4; ++ks) {
        const float* p = A + (size_t)nc * 128 + ks * 32 + lg * 8;
        float4 a0 = *reinterpret_cast<const float4*>(p);
        float4 a1 = *reinterpret_cast<const float4*>(p + 4);
        bfr[ks] = cvt8(a0, a1);
    }

    const int swz = (nloc & 7) << 4;

    u16x8 sreg[8];
    #pragma unroll
    for (int j = 0; j < 8; ++j)
        sreg[j] = *reinterpret_cast<const u16x8*>(Bp + (size_t)(j * 256 + t) * 8);

    u16x8 snext;

    #pragma unroll
    for (int p = 0; p < 4; ++p) {
        #pragma unroll
        for (int j = 0; j < 8; ++j)
            *reinterpret_cast<u16x8*>(slab + (size_t)(j * 256 + t) * 8) = sreg[j];
        __syncthreads();
        if (p < 3) {
            const unsigned short* src = Bp + (size_t)(p + 1) * 16384;
            #pragma unroll
            for (int j = 0; j < 8; ++j)
                sreg[j] = *reinterpret_cast<const u16x8*>(src + (size_t)(j * 256 + t) * 8);
        } else {
            snext = *reinterpret_cast<const u16x8*>(Bp + (size_t)65536 + (size_t)t * 8);
        }
        const bool isPool = (p < 2);
        #pragma unroll
        for (int i = 0; i < 8; ++i) {
            const int ni = p * 8 + i;
            f32x4 acc = (f32x4){0.f, 0.f, 0.f, 0.f};
            #pragma unroll
            for (int ks = 0; ks < 4; ++ks) {
                bf16x8 wf = *reinterpret_cast<const bf16x8*>(
                    slab + (size_t)((i * 4 + ks) * 64 + lane) * 8);
                acc = __builtin_amdgcn_mfma_f32_16x16x32_bf16(wf, bfr[ks], acc, 0, 0, 0);
            }
            const int cni = isPool ? ni : (ni - 16);
            u16x4 o;
            if (isPool) {
                o[0] = f2b(acc[0]); o[1] = f2b(acc[1]);
                o[2] = f2b(acc[2]); o[3] = f2b(acc[3]);
            } else {
                float4 bv = *reinterpret_cast<const float4*>(bres + cni * 16 + lg * 4);
                o[0] = f2b(acc[0] + bv.x); o[1] = f2b(acc[1] + bv.y);
                o[2] = f2b(acc[2] + bv.z); o[3] = f2b(acc[3] + bv.w);
            }
            *reinterpret_cast<u16x4*>(bounce + nloc * 512 + ((cni * 32 + lg * 8) ^ swz)) = o;
        }
        __syncthreads();
        if (p == 1) {
            unsigned short* __restrict__ dst = ga.pool[rsel];
            #pragma unroll
            for (int i = 0; i < 8; ++i) {
                const int chunk = i * 256 + t;
                const int row = chunk >> 5;
                const int c16 = chunk & 31;
                const int byte = row * 512 + ((c16 * 16) ^ ((row & 7) << 4));
                u16x8 v = *reinterpret_cast<const u16x8*>(bounce + byte);
                if (m0 + row < Nrows)
                    *reinterpret_cast<u16x8*>(dst + (size_t)(m0 + row) * 256 + c16 * 8) = v;
            }
            __syncthreads();
        }
    }
    *reinterpret_cast<u16x8*>(slab + (size_t)t * 8) = snext;
    {
        unsigned short* __restrict__ dst = ga.resid[rsel];
        #pragma unroll
        for (int i = 0; i < 8; ++i) {
            const int chunk = i * 256 + t;
            const int row = chunk >> 5;
            const int c16 = chunk & 31;
            const int byte = row * 512 + ((c16 * 16) ^ ((row & 7) << 4));
            u16x8 v = *reinterpret_cast<const u16x8*>(bounce + byte);
            if (m0 + row < Nrows)
                *reinterpret_cast<u16x8*>(dst + (size_t)(m0 + row) * 256 + c16 * 8) = v;
        }
    }
    __syncthreads();
    {
        f32x4 acc = (f32x4){0.f, 0.f, 0.f, 0.f};
        #pragma unroll
        for (int ks = 0; ks < 4; ++ks) {
            bf16x8 wf = *reinterpret_cast<const bf16x8*>(
                slab + (size_t)(ks * 64 + lane) * 8);
            acc = __builtin_amdgcn_mfma_f32_16x16x32_bf16(wf, bfr[ks], acc, 0, 0, 0);
        }
        if (valid) {
            float4 v = make_float4(acc[0], acc[1], acc[2], acc[3]);
            if (lg < 2)
                *reinterpret_cast<float4*>(ga.elOut[rsel] + (size_t)node * 8 + lg * 4) = v;
            else
                *reinterpret_cast<float4*>(ga.erOut[rsel] + (size_t)node * 8 + (lg - 2) * 4) = v;
        }
    }
}

// ---------------------------------------------------------------------------
// CSR build (batched over 4 relations via blockIdx.y)
// ---------------------------------------------------------------------------
struct EdgePtrs {
    const int* src[4];
    const int* dst[4];
    int E[4];
    int csrOff[4];
};

__global__ __launch_bounds__(256)
void hist_k(EdgePtrs ep, int* __restrict__ counts4, int N)
{
    const int r = blockIdx.y;
    const int e = blockIdx.x * 256 + threadIdx.x;
    if (e < ep.E[r]) atomicAdd(counts4 + (size_t)r * N + ep.dst[r][e], 1);
}

__global__ __launch_bounds__(256)
void blksum_k(const int* __restrict__ counts4, int* __restrict__ blksum4, int N)
{
    const int r = blockIdx.y;
    const int* c = counts4 + (size_t)r * N;
    const int base = blockIdx.x * 1024 + threadIdx.x;
    int s = 0;
    #pragma unroll
    for (int i = 0; i < 4; ++i) { int idx = base + i * 256; if (idx < N) s += c[idx]; }
    __shared__ int sd[256];
    sd[threadIdx.x] = s; __syncthreads();
    for (int off = 128; off > 0; off >>= 1) {
        if (threadIdx.x < off) sd[threadIdx.x] += sd[threadIdx.x + off];
        __syncthreads();
    }
    if (threadIdx.x == 0) blksum4[r * 1024 + blockIdx.x] = sd[0];
}

__global__ __launch_bounds__(1024)
void scanblk_k(int* __restrict__ blksum4, int nbx)
{
    const int r = blockIdx.x;
    const int t = threadIdx.x;
    __shared__ int sd[1024];
    int v = (t < nbx) ? blksum4[r * 1024 + t] : 0;
    sd[t] = v; __syncthreads();
    for (int off = 1; off < 1024; off <<= 1) {
        int u = (t >= off) ? sd[t - off] : 0;
        __syncthreads();
        sd[t] += u;
        __syncthreads();
    }
    if (t < nbx) blksum4[r * 1024 + t] = sd[t] - v;
}

__global__ __launch_bounds__(256)
void cursor_k(const int* __restrict__ counts4, const int* __restrict__ blkoff4,
              int* __restrict__ cursor4, int N)
{
    const int r = blockIdx.y;
    const int* c = counts4 + (size_t)r * N;
    int* cur = cursor4 + (size_t)r * N;
    const int t = threadIdx.x;
    const int base = blockIdx.x * 1024 + t * 4;
    const int c0 = (base + 0 < N) ? c[base + 0] : 0;
    const int c1 = (base + 1 < N) ? c[base + 1] : 0;
    const int c2 = (base + 2 < N) ? c[base + 2] : 0;
    const int c3 = (base + 3 < N) ? c[base + 3] : 0;
    const int tsum = c0 + c1 + c2 + c3;
    __shared__ int sd[256];
    sd[t] = tsum; __syncthreads();
    for (int off = 1; off < 256; off <<= 1) {
        int u = (t >= off) ? sd[t - off] : 0;
        __syncthreads();
        sd[t] += u;
        __syncthreads();
    }
    int excl = sd[t] - tsum + blkoff4[r * 1024 + blockIdx.x];
    if (base + 0 < N) cur[base + 0] = excl;
    if (base + 1 < N) cur[base + 1] = excl + c0;
    if (base + 2 < N) cur[base + 2] = excl + c0 + c1;
    if (base + 3 < N) cur[base + 3] = excl + c0 + c1 + c2;
}

__global__ __launch_bounds__(256)
void scatter_k(EdgePtrs ep, int* __restrict__ cursor4, int* __restrict__ csr_src, int N)
{
    const int r = blockIdx.y;
    const int e = blockIdx.x * 256 + threadIdx.x;
    if (e < ep.E[r]) {
        const int d = ep.dst[r][e];
        const int pos = atomicAdd(cursor4 + (size_t)r * N + d, 1);
        csr_src[ep.csrOff[r] + pos] = ep.src[r][e];
    }
}

// ---------------------------------------------------------------------------
// Fused per-node kernel (R13 structure) + first-chunk csr prefetch:
// all 4 relations' first 4-edge index loads issue at kernel entry (16
// independent requests), removing the leading csr->gather dependency from
// each of the 4 serial relation bursts. No masked pool/el loads.
// ---------------------------------------------------------------------------
struct NodeArgs {
    const int* csr[4];
    const int* cursor[4];
    const int* counts[4];
    const float* el[4];
    const float* er[4];
    const unsigned short* pool[4];
    const unsigned short* resid[4];
};

__global__ __launch_bounds__(256)
void node_k(NodeArgs na,
            const float* __restrict__ attn_ui, const float* __restrict__ attn_ii,
            const float* __restrict__ attn_iir,
            const float* __restrict__ a_user, const float* __restrict__ a_item,
            float* __restrict__ out, int Nrows)
{
    const int lane = threadIdx.x & 63;
    const int n = blockIdx.x * 4 + (threadIdx.x >> 6);
    if (n >= Nrows) return;
    const unsigned k = (unsigned)(lane >> 3);
    const unsigned c4 = (unsigned)(lane * 4);

    int deg[4], start[4];
    float erk[4];
    #pragma unroll
    for (int r = 0; r < 4; ++r) {
        deg[r]  = na.counts[r][n];
        const int endv = na.cursor[r][n];
        start[r] = endv - deg[r];
        erk[r]  = na.er[r][(size_t)n * 8 + k];
    }

    // prefetch first 4-edge chunk of ALL relations (16 independent loads)
    int pidx[4][4];
    #pragma unroll
    for (int r = 0; r < 4; ++r) {
        const int dm1 = deg[r] - 1;
        #pragma unroll
        for (int u = 0; u < 4; ++u) {
            const int cc = (u < dm1) ? u : (dm1 > 0 ? dm1 : 0);
            pidx[r][u] = (deg[r] > 0) ? na.csr[r][start[r] + ((u <= dm1) ? u : 0)] : 0;
            (void)cc;
        }
    }

    const float si = 1.f / (1.f + __expf(-a_item[0])), osi = 1.f - si;
    const float su = 1.f / (1.f + __expf(-a_user[0])), osu = 1.f - su;

    float4 fr[4];
    #pragma unroll
    for (int r = 0; r < 4; ++r) {
        const int d = deg[r];
        const int st = start[r];
        const int* __restrict__ csr = na.csr[r];
        const float* __restrict__ elr = na.el[r];
        const unsigned short* __restrict__ fs = na.pool[r];
        const float er_k = erk[r];
        float s = 0.f;
        float4 acc = make_float4(0.f, 0.f, 0.f, 0.f);

        // peeled first chunk (prefetched indices)
        if (d > 0) {
            const int m = d < 4 ? d : 4;
            float ex[4];
            #pragma unroll
            for (int u = 0; u < 4; ++u) {
                const float x = elr[(unsigned)pidx[r][u] * 8u + k] + er_k;
                const float e = __builtin_amdgcn_exp2f(fmaxf(x, NEG_SLOPE * x));
                ex[u] = (u < m) ? e : 0.f;
            }
            float4 pv[4];
            #pragma unroll
            for (int u = 0; u < 4; ++u)
                pv[u] = load4b(fs + (unsigned)pidx[r][u] * 256u + c4);
            #pragma unroll
            for (int u = 0; u < 4; ++u) {
                s += ex[u];
                acc.x = fmaf(pv[u].x, ex[u], acc.x);
                acc.y = fmaf(pv[u].y, ex[u], acc.y);
                acc.z = fmaf(pv[u].z, ex[u], acc.z);
                acc.w = fmaf(pv[u].w, ex[u], acc.w);
            }
        }
        // remaining chunks (loaded in-loop)
        for (int base = 4; base < d; base += 4) {
            const int m = d - base;
            int sidx[4];
            #pragma unroll
            for (int u = 0; u < 4; ++u)
                sidx[u] = csr[st + base + ((u < m) ? u : 0)];
            float ex[4];
            #pragma unroll
            for (int u = 0; u < 4; ++u) {
                const float x = elr[(unsigned)sidx[u] * 8u + k] + er_k;
                const float e = __builtin_amdgcn_exp2f(fmaxf(x, NEG_SLOPE * x));
                ex[u] = (u < m) ? e : 0.f;
            }
            float4 pv[4];
            #pragma unroll
            for (int u = 0; u < 4; ++u)
                pv[u] = load4b(fs + (unsigned)sidx[u] * 256u + c4);
            #pragma unroll
            for (int u = 0; u < 4; ++u) {
                s += ex[u];
                acc.x = fmaf(pv[u].x, ex[u], acc.x);
                acc.y = fmaf(pv[u].y, ex[u], acc.y);
                acc.z = fmaf(pv[u].z, ex[u], acc.z);
                acc.w = fmaf(pv[u].w, ex[u], acc.w);
            }
        }
        const float inv = (d > 0) ? 1.f / s : 0.f;
        float4 R = load4b(na.resid[r] + (unsigned)n * 256u + c4);
        const float sg = (r == 1) ? su : si;
        const float og = (r == 1) ? osu : osi;
        fr[r].x = sg * fmaxf(acc.x * inv, 0.f) + og * R.x;
        fr[r].y = sg * fmaxf(acc.y * inv, 0.f) + og * R.y;
        fr[r].z = sg * fmaxf(acc.z * inv, 0.f) + og * R.z;
        fr[r].w = sg * fmaxf(acc.w * inv, 0.f) + og * R.w;
    }

    const float4 f0 = fr[0], f1 = fr[2], f2 = fr[3], fiu = fr[1];
    float4 w0 = *reinterpret_cast<const float4*>(attn_ui  + lane * 4);
    float4 w1 = *reinterpret_cast<const float4*>(attn_ii  + lane * 4);
    float4 w2 = *reinterpret_cast<const float4*>(attn_iir + lane * 4);

    float p[3][3];
    p[0][0] = dot4(w0, f0); p[0][1] = dot4(w0, f1); p[0][2] = dot4(w0, f2);
    p[1][0] = dot4(w1, f0); p[1][1] = dot4(w1, f1); p[1][2] = dot4(w1, f2);
    p[2][0] = dot4(w2, f0); p[2][1] = dot4(w2, f1); p[2][2] = dot4(w2, f2);
    #pragma unroll
    for (int x = 0; x < 3; ++x)
        #pragma unroll
        for (int r = 0; r < 3; ++r)
            #pragma unroll
            for (int m = 1; m < 8; m <<= 1)
                p[x][r] += __shfl_xor(p[x][r], m, 64);

    const size_t NK = (size_t)Nrows * 256;
    const size_t o = (size_t)n * 256 + lane * 4;
    const size_t xoff[3] = {0, 2 * NK, 3 * NK};
    #pragma unroll
    for (int x = 0; x < 3; ++x) {
        float a0 = lrelu(p[x][0]), a1 = lrelu(p[x][1]), a2 = lrelu(p[x][2]);
        float mx = fmaxf(a0, fmaxf(a1, a2));
        float e0 = __expf(a0 - mx), e1 = __expf(a1 - mx), e2 = __expf(a2 - mx);
        float inv = 1.f / (e0 + e1 + e2);
        e0 *= inv; e1 *= inv; e2 *= inv;
        float4 rr;
        rr.x = e0 * f0.x + e1 * f1.x + e2 * f2.x;
        rr.y = e0 * f0.y + e1 * f1.y + e2 * f2.y;
        rr.z = e0 * f0.z + e1 * f1.z + e2 * f2.z;
        rr.w = e0 * f0.w + e1 * f1.w + e2 * f2.w;
        *reinterpret_cast<float4*>(out + xoff[x] + o) = rr;
    }
    *reinterpret_cast<float4*>(out + NK + o) = fiu;
}

// ---------------------------------------------------------------------------
// Relation-level tiny matvecs. wvec pre-scaled by LOG2E; ro NOT scaled.
// ---------------------------------------------------------------------------
struct RelPtrs {
    const float* rf[4];
    const float* Wrel[4];
    const float* Wupd[4];
    const float* bupd[4];
};

__global__ __launch_bounds__(512)
void rel_k(RelPtrs P, float* __restrict__ wvec, float* __restrict__ ro)
{
    const int r = blockIdx.x;
    const int t = threadIdx.x;
    __shared__ float rfs[64];
    if (t < 64) rfs[t] = P.rf[r][t];
    __syncthreads();
    {
        const float* Wc = P.Wrel[r];
        float acc = 0.f;
        #pragma unroll 8
        for (int i = 0; i < 64; ++i) acc = fmaf(rfs[i], Wc[(size_t)i * 512 + t], acc);
        wvec[(size_t)r * 512 + t] = acc * LOG2E;
    }
    if (t < 256) {
        const float* Wc = P.Wupd[r];
        float acc = P.bupd[r][t];
        #pragma unroll 8
        for (int i = 0; i < 64; ++i) acc = fmaf(rfs[i], Wc[(size_t)i * 256 + t], acc);
        ro[(size_t)r * 256 + t] = acc;
    }
}

// ---------------------------------------------------------------------------
extern "C" void kernel_launch(void* const* d_in, const int* in_sizes, int n_in,
                              void* d_out, int out_size, void* d_ws, size_t ws_size,
                              hipStream_t stream)
{
    (void)n_in; (void)out_size; (void)ws_size;
    const float* feat_ui  = (const float*)d_in[0];
    const float* feat_iu  = (const float*)d_in[1];
    const float* feat_ii  = (const float*)d_in[2];
    const float* feat_iir = (const float*)d_in[3];
    const float* W_user   = (const float*)d_in[8];
    const float* W_item   = (const float*)d_in[9];
    const float* Wres_user = (const float*)d_in[18];
    const float* bres_user = (const float*)d_in[19];
    const float* Wres_item = (const float*)d_in[20];
    const float* bres_item = (const float*)d_in[21];
    const float* a_user = (const float*)d_in[22];
    const float* a_item = (const float*)d_in[23];
    const int N = in_sizes[0] / 128;
    const int Es[4] = {in_sizes[32], in_sizes[34], in_sizes[36], in_sizes[38]};
    int maxE = 0;
    for (int r = 0; r < 4; ++r) maxE = Es[r] > maxE ? Es[r] : maxE;

    const size_t NP = (size_t)N * 256;
    const size_t N8 = (size_t)N * 8;
    const size_t BPSZ = 33 * 4 * 64 * 8;              // u16 per relation pack

    unsigned short* us = (unsigned short*)d_ws;
    unsigned short* pool[4];
    unsigned short* resid[4];
    for (int r = 0; r < 4; ++r) pool[r]  = us + (size_t)r * NP;
    for (int r = 0; r < 4; ++r) resid[r] = us + (size_t)(4 + r) * NP;
    unsigned short* BpArr[4];
    for (int r = 0; r < 4; ++r) BpArr[r] = us + 8 * NP + (size_t)r * BPSZ;
    float* fl = (float*)(us + 8 * NP + 4 * BPSZ);
    float *el[4], *er[4];
    for (int r = 0; r < 4; ++r) { el[r] = fl + (size_t)(2 * r) * N8; er[r] = fl + (size_t)(2 * r + 1) * N8; }
    float* wvec = fl + 8 * N8;                        // 4 x 512
    int* counts4 = (int*)(wvec + 4 * 512);
    int* cursor4 = counts4 + 4 * (size_t)N;
    int* blksum4 = cursor4 + 4 * (size_t)N;
    int* csr_src = blksum4 + 4 * 1024;
    float* out = (float*)d_out;

    EdgePtrs ep;
    {
        int off = 0;
        const int si[4] = {32, 34, 36, 38};
        for (int r = 0; r < 4; ++r) {
            ep.src[r] = (const int*)d_in[si[r]];
            ep.dst[r] = (const int*)d_in[si[r] + 1];
            ep.E[r] = Es[r];
            ep.csrOff[r] = off;
            off += Es[r];
        }
    }

    (void)hipMemsetAsync(counts4, 0, 4 * (size_t)N * sizeof(int), stream);

    RelPtrs rp;
    rp.rf[0]   = (const float*)d_in[4];  rp.rf[1]   = (const float*)d_in[5];
    rp.rf[2]   = (const float*)d_in[6];  rp.rf[3]   = (const float*)d_in[7];
    rp.Wrel[0] = (const float*)d_in[10]; rp.Wrel[1] = (const float*)d_in[11];
    rp.Wrel[2] = (const float*)d_in[12]; rp.Wrel[3] = (const float*)d_in[13];
    rp.Wupd[0] = (const float*)d_in[24]; rp.Wupd[1] = (const float*)d_in[26];
    rp.Wupd[2] = (const float*)d_in[28]; rp.Wupd[3] = (const float*)d_in[30];
    rp.bupd[0] = (const float*)d_in[25]; rp.bupd[1] = (const float*)d_in[27];
    rp.bupd[2] = (const float*)d_in[29]; rp.bupd[3] = (const float*)d_in[31];
    rel_k<<<dim3(4), dim3(512), 0, stream>>>(rp, wvec, out + 4 * NP);

    // per-relation weight packs (needs wvec for the score columns)
    const int pair[4] = {1, 0, 3, 2};
    PackArgs pa;
    pa.W1[0] = W_user; pa.W2[0] = Wres_user;
    pa.W1[1] = W_item; pa.W2[1] = Wres_item;
    pa.W1[2] = W_item; pa.W2[2] = Wres_item;
    pa.W1[3] = W_item; pa.W2[3] = Wres_item;
    for (int r = 0; r < 4; ++r) {
        pa.wvA[r] = wvec + (size_t)r * 512;
        pa.wvB[r] = wvec + (size_t)pair[r] * 512;
        pa.Bp[r]  = BpArr[r];
    }
    pack_b_k<<<dim3(33, 4), 256, 0, stream>>>(pa);

    // CSR build
    const int geb = (maxE + 255) / 256;
    const int nbx = (N + 1023) / 1024;
    hist_k<<<dim3(geb, 4), 256, 0, stream>>>(ep, counts4, N);
    blksum_k<<<dim3(nbx, 4), 256, 0, stream>>>(counts4, blksum4, N);
    scanblk_k<<<dim3(4), 1024, 0, stream>>>(blksum4, nbx);
    cursor_k<<<dim3(nbx, 4), 256, 0, stream>>>(counts4, blksum4, cursor4, N);
    scatter_k<<<dim3(geb, 4), 256, 0, stream>>>(ep, cursor4, csr_src, N);

    // operand-swap fused GEMM (pool + resid + el/er), all 4 relations batched
    GemmArgs ga;
    ga.A[0] = feat_iu;  ga.bres[0] = bres_user;
    ga.A[1] = feat_ui;  ga.bres[1] = bres_item;
    ga.A[2] = feat_iir; ga.bres[2] = bres_item;
    ga.A[3] = feat_ii;  ga.bres[3] = bres_item;
    for (int r = 0; r < 4; ++r) {
        ga.Bp[r]    = BpArr[r];
        ga.pool[r]  = pool[r];
        ga.resid[r] = resid[pair[r]];
        ga.elOut[r] = el[r];
        ga.erOut[r] = er[pair[r]];
    }
    const int gb = (N + 63) / 64;
    mfma_gemm_k<<<dim3(gb, 4), 256, 0, stream>>>(ga, N);

    // fused aggregation + gated residual + cross-relation fusion
    NodeArgs na;
    for (int r = 0; r < 4; ++r) {
        na.csr[r]    = csr_src + ep.csrOff[r];
        na.cursor[r] = cursor4 + (size_t)r * N;
        na.counts[r] = counts4 + (size_t)r * N;
        na.el[r]     = el[r];
        na.er[r]     = er[r];
        na.pool[r]   = pool[r];
        na.resid[r]  = resid[r];
    }
    const int nb4 = (N + 3) / 4;
    node_k<<<nb4, 256, 0, stream>>>(na,
                                    (const float*)d_in[14], (const float*)d_in[16],
                                    (const float*)d_in[17],
                                    a_user, a_item, out, N);
}

// Round 16
// 557.607 us; speedup vs baseline: 1.2258x; 1.0260x over previous
//
#include <hip/hip_runtime.h>
#include <hip/hip_bf16.h>
#include <math.h>

#define NEG_SLOPE 0.2f
#define LOG2E 1.4426950408889634f

using bf16x8 = __attribute__((ext_vector_type(8))) short;
using f32x4  = __attribute__((ext_vector_type(4))) float;
using u16x8  = __attribute__((ext_vector_type(8))) unsigned short;
using u16x4  = __attribute__((ext_vector_type(4))) unsigned short;

__device__ __forceinline__ float lrelu(float x) { return x > 0.f ? x : NEG_SLOPE * x; }
__device__ __forceinline__ float dot4(float4 a, float4 b) {
    return a.x * b.x + a.y * b.y + a.z * b.z + a.w * b.w;
}
__device__ __forceinline__ unsigned short f2b(float x) {
    union { float f; unsigned u; } v; v.f = x;
    unsigned r = v.u + 0x7fff + ((v.u >> 16) & 1);
    return (unsigned short)(r >> 16);
}
__device__ __forceinline__ float b2f(unsigned short b) {
    union { unsigned u; float f; } v; v.u = ((unsigned)b) << 16;
    return v.f;
}
__device__ __forceinline__ float4 load4b(const unsigned short* p) {
    u16x4 u = *reinterpret_cast<const u16x4*>(p);
    return make_float4(b2f(u[0]), b2f(u[1]), b2f(u[2]), b2f(u[3]));
}
__device__ __forceinline__ bf16x8 cvt8(float4 a0, float4 a1) {
    union { u16x8 u; bf16x8 b; } c;
    c.u[0] = f2b(a0.x); c.u[1] = f2b(a0.y); c.u[2] = f2b(a0.z); c.u[3] = f2b(a0.w);
    c.u[4] = f2b(a1.x); c.u[5] = f2b(a1.y); c.u[6] = f2b(a1.z); c.u[7] = f2b(a1.w);
    return c.b;
}

// ---------------------------------------------------------------------------
// Pack per-relation Wcat[128 x 528] into MFMA fragment-linear bf16:
//   cols 0-255 = W1 (pool), 256-511 = W2 (resid),
//   512-519 = wel[k][h], 520-527 = wer[k][h]  (score columns; wvec prescaled)
// ---------------------------------------------------------------------------
struct PackArgs {
    const float* W1[4];
    const float* W2[4];
    const float* wvA[4];
    const float* wvB[4];
    unsigned short* Bp[4];
};

__global__ __launch_bounds__(256)
void pack_b_k(PackArgs pa)
{
    const int r = blockIdx.y;
    const int nb = blockIdx.x;                 // 0..32
    const int ks = threadIdx.x >> 6;
    const int lane = threadIdx.x & 63;
    const int n = nb * 16 + (lane & 15);
    const int k0 = ks * 32 + (lane >> 4) * 8;
    u16x8 u;
    if (n < 512) {
        const float* Wsrc = (n < 256) ? (pa.W1[r] + n) : (pa.W2[r] + (n - 256));
        #pragma unroll
        for (int e = 0; e < 8; ++e) u[e] = f2b(Wsrc[(size_t)(k0 + e) * 256]);
    } else {
        const int h = (n - 512) & 7;
        const bool isEr = (n >= 520);
        const float* wv = isEr ? (pa.wvB[r] + h * 64 + 32) : (pa.wvA[r] + h * 64);
        const float* Wc = pa.W1[r] + h * 32;
        #pragma unroll
        for (int e = 0; e < 8; ++e) {
            const size_t k = (size_t)(k0 + e);
            float s = 0.f;
            #pragma unroll 8
            for (int d = 0; d < 32; ++d) s = fmaf(Wc[k * 256 + d], wv[d], s);
            u[e] = f2b(s);
        }
    }
    const size_t gid = (size_t)((nb * 4 + ks) * 64 + lane);
    *reinterpret_cast<u16x8*>(pa.Bp[r] + gid * 8) = u;
}

// ---------------------------------------------------------------------------
// Operand-swap MFMA GEMM, Bp staged through LDS in 32 KB phases.
// 48 KB LDS total (32K slab + 16K bounce, flush every phase) -> 3 blocks/CU
// (R13/15 used 64 KB -> 2 blocks/CU). 2 barriers per phase.
// ---------------------------------------------------------------------------
struct GemmArgs {
    const float* A[4];
    const unsigned short* Bp[4];
    const float* bres[4];
    unsigned short* pool[4];
    unsigned short* resid[4];    // resid[pair[r]] slot
    float* elOut[4];             // el[r]
    float* erOut[4];             // er[pair[r]]
};

__global__ __launch_bounds__(256)
void mfma_gemm_k(GemmArgs ga, int Nrows)
{
    __shared__ __align__(16) char smem[49152];
    unsigned short* slab = (unsigned short*)smem;        // 32 KB
    char* bounce = smem + 32768;                         // 16 KB (64 nodes x 256 B)
    const int rsel = blockIdx.y;
    const int t = threadIdx.x;
    const int wv = t >> 6, lane = t & 63;
    const int l15 = lane & 15, lg = lane >> 4;
    const int nloc = wv * 16 + l15;              // 0..63
    const int m0 = blockIdx.x * 64;
    const int node = m0 + nloc;
    const bool valid = node < Nrows;
    const int nc = valid ? node : (Nrows - 1);

    const float* __restrict__ A = ga.A[rsel];
    const unsigned short* __restrict__ Bp = ga.Bp[rsel];
    const float* __restrict__ bres = ga.bres[rsel];

    bf16x8 bfr[4];
    #pragma unroll
    for (int ks = 0; ks < 4; ++ks) {
        const float* p = A + (size_t)nc * 128 + ks * 32 + lg * 8;
        float4 a0 = *reinterpret_cast<const float4*>(p);
        float4 a1 = *reinterpret_cast<const float4*>(p + 4);
        bfr[ks] = cvt8(a0, a1);
    }

    const int swz = (nloc & 7) << 4;

    u16x8 sreg[8];
    #pragma unroll
    for (int j = 0; j < 8; ++j)
        sreg[j] = *reinterpret_cast<const u16x8*>(Bp + (size_t)(j * 256 + t) * 8);

    u16x8 snext;

    #pragma unroll
    for (int p = 0; p < 4; ++p) {
        // 1. write staged slab
        #pragma unroll
        for (int j = 0; j < 8; ++j)
            *reinterpret_cast<u16x8*>(slab + (size_t)(j * 256 + t) * 8) = sreg[j];
        __syncthreads();   // A: slab visible; prior flush reads of bounce done
        // 2. issue next-phase loads early
        if (p < 3) {
            const unsigned short* src = Bp + (size_t)(p + 1) * 16384;
            #pragma unroll
            for (int j = 0; j < 8; ++j)
                sreg[j] = *reinterpret_cast<const u16x8*>(src + (size_t)(j * 256 + t) * 8);
        } else {
            snext = *reinterpret_cast<const u16x8*>(Bp + (size_t)65536 + (size_t)t * 8);
        }
        // 3. compute 8 ni columns, frags -> 16 KB bounce (swizzled)
        const bool isPool = (p < 2);
        #pragma unroll
        for (int i = 0; i < 8; ++i) {
            f32x4 acc = (f32x4){0.f, 0.f, 0.f, 0.f};
            #pragma unroll
            for (int ks = 0; ks < 4; ++ks) {
                bf16x8 wf = *reinterpret_cast<const bf16x8*>(
                    slab + (size_t)((i * 4 + ks) * 64 + lane) * 8);
                acc = __builtin_amdgcn_mfma_f32_16x16x32_bf16(wf, bfr[ks], acc, 0, 0, 0);
            }
            u16x4 o;
            if (isPool) {
                o[0] = f2b(acc[0]); o[1] = f2b(acc[1]);
                o[2] = f2b(acc[2]); o[3] = f2b(acc[3]);
            } else {
                const int cb = (p - 2) * 128 + i * 16 + lg * 4;
                float4 bv = *reinterpret_cast<const float4*>(bres + cb);
                o[0] = f2b(acc[0] + bv.x); o[1] = f2b(acc[1] + bv.y);
                o[2] = f2b(acc[2] + bv.z); o[3] = f2b(acc[3] + bv.w);
            }
            *reinterpret_cast<u16x4*>(bounce + nloc * 256 + ((i * 32 + lg * 8) ^ swz)) = o;
        }
        __syncthreads();   // B: bounce complete; slab reads done
        // 4. flush this phase's 128 channels (coalesced u16x8)
        {
            unsigned short* __restrict__ dst = isPool ? ga.pool[rsel] : ga.resid[rsel];
            const int colbase = (p & 1) * 128;
            #pragma unroll
            for (int it = 0; it < 4; ++it) {
                const int chunk = it * 256 + t;      // 0..1023 16B chunks
                const int row = chunk >> 4;          // 16 chunks per 256B row
                const int c16 = chunk & 15;
                const int byte = row * 256 + ((c16 * 16) ^ ((row & 7) << 4));
                u16x8 v = *reinterpret_cast<const u16x8*>(bounce + byte);
                if (m0 + row < Nrows)
                    *reinterpret_cast<u16x8*>(dst + (size_t)(m0 + row) * 256
                                              + colbase + c16 * 8) = v;
            }
        }
        // no barrier: next phase's barrier A protects bounce reuse
    }
    // score slab (4 KB) -> slab region; barrier; score MFMA
    *reinterpret_cast<u16x8*>(slab + (size_t)t * 8) = snext;
    __syncthreads();
    {
        f32x4 acc = (f32x4){0.f, 0.f, 0.f, 0.f};
        #pragma unroll
        for (int ks = 0; ks < 4; ++ks) {
            bf16x8 wf = *reinterpret_cast<const bf16x8*>(
                slab + (size_t)(ks * 64 + lane) * 8);
            acc = __builtin_amdgcn_mfma_f32_16x16x32_bf16(wf, bfr[ks], acc, 0, 0, 0);
        }
        if (valid) {
            float4 v = make_float4(acc[0], acc[1], acc[2], acc[3]);
            if (lg < 2)
                *reinterpret_cast<float4*>(ga.elOut[rsel] + (size_t)node * 8 + lg * 4) = v;
            else
                *reinterpret_cast<float4*>(ga.erOut[rsel] + (size_t)node * 8 + (lg - 2) * 4) = v;
        }
    }
}

// ---------------------------------------------------------------------------
// CSR build (batched over 4 relations via blockIdx.y)
// ---------------------------------------------------------------------------
struct EdgePtrs {
    const int* src[4];
    const int* dst[4];
    int E[4];
    int csrOff[4];
};

__global__ __launch_bounds__(256)
void hist_k(EdgePtrs ep, int* __restrict__ counts4, int N)
{
    const int r = blockIdx.y;
    const int e = blockIdx.x * 256 + threadIdx.x;
    if (e < ep.E[r]) atomicAdd(counts4 + (size_t)r * N + ep.dst[r][e], 1);
}

__global__ __launch_bounds__(256)
void blksum_k(const int* __restrict__ counts4, int* __restrict__ blksum4, int N)
{
    const int r = blockIdx.y;
    const int* c = counts4 + (size_t)r * N;
    const int base = blockIdx.x * 1024 + threadIdx.x;
    int s = 0;
    #pragma unroll
    for (int i = 0; i < 4; ++i) { int idx = base + i * 256; if (idx < N) s += c[idx]; }
    __shared__ int sd[256];
    sd[threadIdx.x] = s; __syncthreads();
    for (int off = 128; off > 0; off >>= 1) {
        if (threadIdx.x < off) sd[threadIdx.x] += sd[threadIdx.x + off];
        __syncthreads();
    }
    if (threadIdx.x == 0) blksum4[r * 1024 + blockIdx.x] = sd[0];
}

__global__ __launch_bounds__(1024)
void scanblk_k(int* __restrict__ blksum4, int nbx)
{
    const int r = blockIdx.x;
    const int t = threadIdx.x;
    __shared__ int sd[1024];
    int v = (t < nbx) ? blksum4[r * 1024 + t] : 0;
    sd[t] = v; __syncthreads();
    for (int off = 1; off < 1024; off <<= 1) {
        int u = (t >= off) ? sd[t - off] : 0;
        __syncthreads();
        sd[t] += u;
        __syncthreads();
    }
    if (t < nbx) blksum4[r * 1024 + t] = sd[t] - v;
}

__global__ __launch_bounds__(256)
void cursor_k(const int* __restrict__ counts4, const int* __restrict__ blkoff4,
              int* __restrict__ cursor4, int N)
{
    const int r = blockIdx.y;
    const int* c = counts4 + (size_t)r * N;
    int* cur = cursor4 + (size_t)r * N;
    const int t = threadIdx.x;
    const int base = blockIdx.x * 1024 + t * 4;
    const int c0 = (base + 0 < N) ? c[base + 0] : 0;
    const int c1 = (base + 1 < N) ? c[base + 1] : 0;
    const int c2 = (base + 2 < N) ? c[base + 2] : 0;
    const int c3 = (base + 3 < N) ? c[base + 3] : 0;
    const int tsum = c0 + c1 + c2 + c3;
    __shared__ int sd[256];
    sd[t] = tsum; __syncthreads();
    for (int off = 1; off < 256; off <<= 1) {
        int u = (t >= off) ? sd[t - off] : 0;
        __syncthreads();
        sd[t] += u;
        __syncthreads();
    }
    int excl = sd[t] - tsum + blkoff4[r * 1024 + blockIdx.x];
    if (base + 0 < N) cur[base + 0] = excl;
    if (base + 1 < N) cur[base + 1] = excl + c0;
    if (base + 2 < N) cur[base + 2] = excl + c0 + c1;
    if (base + 3 < N) cur[base + 3] = excl + c0 + c1 + c2;
}

__global__ __launch_bounds__(256)
void scatter_k(EdgePtrs ep, int* __restrict__ cursor4, int* __restrict__ csr_src, int N)
{
    const int r = blockIdx.y;
    const int e = blockIdx.x * 256 + threadIdx.x;
    if (e < ep.E[r]) {
        const int d = ep.dst[r][e];
        const int pos = atomicAdd(cursor4 + (size_t)r * N + d, 1);
        csr_src[ep.csrOff[r] + pos] = ep.src[r][e];
    }
}

// ---------------------------------------------------------------------------
// Fused per-node kernel (R13/R15 structure, frozen).
// ---------------------------------------------------------------------------
struct NodeArgs {
    const int* csr[4];
    const int* cursor[4];
    const int* counts[4];
    const float* el[4];
    const float* er[4];
    const unsigned short* pool[4];
    const unsigned short* resid[4];
};

__global__ __launch_bounds__(256)
void node_k(NodeArgs na,
            const float* __restrict__ attn_ui, const float* __restrict__ attn_ii,
            const float* __restrict__ attn_iir,
            const float* __restrict__ a_user, const float* __restrict__ a_item,
            float* __restrict__ out, int Nrows)
{
    const int lane = threadIdx.x & 63;
    const int n = blockIdx.x * 4 + (threadIdx.x >> 6);
    if (n >= Nrows) return;
    const unsigned k = (unsigned)(lane >> 3);
    const unsigned c4 = (unsigned)(lane * 4);

    int deg[4], start[4];
    float erk[4];
    #pragma unroll
    for (int r = 0; r < 4; ++r) {
        deg[r]  = na.counts[r][n];
        const int endv = na.cursor[r][n];
        start[r] = endv - deg[r];
        erk[r]  = na.er[r][(size_t)n * 8 + k];
    }

    const float si = 1.f / (1.f + __expf(-a_item[0])), osi = 1.f - si;
    const float su = 1.f / (1.f + __expf(-a_user[0])), osu = 1.f - su;

    float4 fr[4];
    #pragma unroll
    for (int r = 0; r < 4; ++r) {
        const int d = deg[r];
        const int st = start[r];
        const int* __restrict__ csr = na.csr[r];
        const float* __restrict__ elr = na.el[r];
        const unsigned short* __restrict__ fs = na.pool[r];
        const float er_k = erk[r];
        float s = 0.f;
        float4 acc = make_float4(0.f, 0.f, 0.f, 0.f);
        for (int base = 0; base < d; base += 4) {
            const int m = d - base;
            int sidx[4];
            #pragma unroll
            for (int u = 0; u < 4; ++u)
                sidx[u] = csr[st + base + ((u < m) ? u : 0)];
            float ex[4];
            #pragma unroll
            for (int u = 0; u < 4; ++u) {
                const float x = elr[(unsigned)sidx[u] * 8u + k] + er_k;
                const float e = __builtin_amdgcn_exp2f(fmaxf(x, NEG_SLOPE * x));
                ex[u] = (u < m) ? e : 0.f;
            }
            float4 pv[4];
            #pragma unroll
            for (int u = 0; u < 4; ++u)
                pv[u] = load4b(fs + (unsigned)sidx[u] * 256u + c4);
            #pragma unroll
            for (int u = 0; u < 4; ++u) {
                s += ex[u];
                acc.x = fmaf(pv[u].x, ex[u], acc.x);
                acc.y = fmaf(pv[u].y, ex[u], acc.y);
                acc.z = fmaf(pv[u].z, ex[u], acc.z);
                acc.w = fmaf(pv[u].w, ex[u], acc.w);
            }
        }
        const float inv = (d > 0) ? 1.f / s : 0.f;
        float4 R = load4b(na.resid[r] + (unsigned)n * 256u + c4);
        const float sg = (r == 1) ? su : si;
        const float og = (r == 1) ? osu : osi;
        fr[r].x = sg * fmaxf(acc.x * inv, 0.f) + og * R.x;
        fr[r].y = sg * fmaxf(acc.y * inv, 0.f) + og * R.y;
        fr[r].z = sg * fmaxf(acc.z * inv, 0.f) + og * R.z;
        fr[r].w = sg * fmaxf(acc.w * inv, 0.f) + og * R.w;
    }

    const float4 f0 = fr[0], f1 = fr[2], f2 = fr[3], fiu = fr[1];
    float4 w0 = *reinterpret_cast<const float4*>(attn_ui  + lane * 4);
    float4 w1 = *reinterpret_cast<const float4*>(attn_ii  + lane * 4);
    float4 w2 = *reinterpret_cast<const float4*>(attn_iir + lane * 4);

    float p[3][3];
    p[0][0] = dot4(w0, f0); p[0][1] = dot4(w0, f1); p[0][2] = dot4(w0, f2);
    p[1][0] = dot4(w1, f0); p[1][1] = dot4(w1, f1); p[1][2] = dot4(w1, f2);
    p[2][0] = dot4(w2, f0); p[2][1] = dot4(w2, f1); p[2][2] = dot4(w2, f2);
    #pragma unroll
    for (int x = 0; x < 3; ++x)
        #pragma unroll
        for (int r = 0; r < 3; ++r)
            #pragma unroll
            for (int m = 1; m < 8; m <<= 1)
                p[x][r] += __shfl_xor(p[x][r], m, 64);

    const size_t NK = (size_t)Nrows * 256;
    const size_t o = (size_t)n * 256 + lane * 4;
    const size_t xoff[3] = {0, 2 * NK, 3 * NK};
    #pragma unroll
    for (int x = 0; x < 3; ++x) {
        float a0 = lrelu(p[x][0]), a1 = lrelu(p[x][1]), a2 = lrelu(p[x][2]);
        float mx = fmaxf(a0, fmaxf(a1, a2));
        float e0 = __expf(a0 - mx), e1 = __expf(a1 - mx), e2 = __expf(a2 - mx);
        float inv = 1.f / (e0 + e1 + e2);
        e0 *= inv; e1 *= inv; e2 *= inv;
        float4 rr;
        rr.x = e0 * f0.x + e1 * f1.x + e2 * f2.x;
        rr.y = e0 * f0.y + e1 * f1.y + e2 * f2.y;
        rr.z = e0 * f0.z + e1 * f1.z + e2 * f2.z;
        rr.w = e0 * f0.w + e1 * f1.w + e2 * f2.w;
        *reinterpret_cast<float4*>(out + xoff[x] + o) = rr;
    }
    *reinterpret_cast<float4*>(out + NK + o) = fiu;
}

// ---------------------------------------------------------------------------
// Relation-level tiny matvecs. wvec pre-scaled by LOG2E; ro NOT scaled.
// ---------------------------------------------------------------------------
struct RelPtrs {
    const float* rf[4];
    const float* Wrel[4];
    const float* Wupd[4];
    const float* bupd[4];
};

__global__ __launch_bounds__(512)
void rel_k(RelPtrs P, float* __restrict__ wvec, float* __restrict__ ro)
{
    const int r = blockIdx.x;
    const int t = threadIdx.x;
    __shared__ float rfs[64];
    if (t < 64) rfs[t] = P.rf[r][t];
    __syncthreads();
    {
        const float* Wc = P.Wrel[r];
        float acc = 0.f;
        #pragma unroll 8
        for (int i = 0; i < 64; ++i) acc = fmaf(rfs[i], Wc[(size_t)i * 512 + t], acc);
        wvec[(size_t)r * 512 + t] = acc * LOG2E;
    }
    if (t < 256) {
        const float* Wc = P.Wupd[r];
        float acc = P.bupd[r][t];
        #pragma unroll 8
        for (int i = 0; i < 64; ++i) acc = fmaf(rfs[i], Wc[(size_t)i * 256 + t], acc);
        ro[(size_t)r * 256 + t] = acc;
    }
}

// ---------------------------------------------------------------------------
extern "C" void kernel_launch(void* const* d_in, const int* in_sizes, int n_in,
                              void* d_out, int out_size, void* d_ws, size_t ws_size,
                              hipStream_t stream)
{
    (void)n_in; (void)out_size; (void)ws_size;
    const float* feat_ui  = (const float*)d_in[0];
    const float* feat_iu  = (const float*)d_in[1];
    const float* feat_ii  = (const float*)d_in[2];
    const float* feat_iir = (const float*)d_in[3];
    const float* W_user   = (const float*)d_in[8];
    const float* W_item   = (const float*)d_in[9];
    const float* Wres_user = (const float*)d_in[18];
    const float* bres_user = (const float*)d_in[19];
    const float* Wres_item = (const float*)d_in[20];
    const float* bres_item = (const float*)d_in[21];
    const float* a_user = (const float*)d_in[22];
    const float* a_item = (const float*)d_in[23];
    const int N = in_sizes[0] / 128;
    const int Es[4] = {in_sizes[32], in_sizes[34], in_sizes[36], in_sizes[38]};
    int maxE = 0;
    for (int r = 0; r < 4; ++r) maxE = Es[r] > maxE ? Es[r] : maxE;

    const size_t NP = (size_t)N * 256;
    const size_t N8 = (size_t)N * 8;
    const size_t BPSZ = 33 * 4 * 64 * 8;              // u16 per relation pack

    unsigned short* us = (unsigned short*)d_ws;
    unsigned short* pool[4];
    unsigned short* resid[4];
    for (int r = 0; r < 4; ++r) pool[r]  = us + (size_t)r * NP;
    for (int r = 0; r < 4; ++r) resid[r] = us + (size_t)(4 + r) * NP;
    unsigned short* BpArr[4];
    for (int r = 0; r < 4; ++r) BpArr[r] = us + 8 * NP + (size_t)r * BPSZ;
    float* fl = (float*)(us + 8 * NP + 4 * BPSZ);
    float *el[4], *er[4];
    for (int r = 0; r < 4; ++r) { el[r] = fl + (size_t)(2 * r) * N8; er[r] = fl + (size_t)(2 * r + 1) * N8; }
    float* wvec = fl + 8 * N8;                        // 4 x 512
    int* counts4 = (int*)(wvec + 4 * 512);
    int* cursor4 = counts4 + 4 * (size_t)N;
    int* blksum4 = cursor4 + 4 * (size_t)N;
    int* csr_src = blksum4 + 4 * 1024;
    float* out = (float*)d_out;

    EdgePtrs ep;
    {
        int off = 0;
        const int si[4] = {32, 34, 36, 38};
        for (int r = 0; r < 4; ++r) {
            ep.src[r] = (const int*)d_in[si[r]];
            ep.dst[r] = (const int*)d_in[si[r] + 1];
            ep.E[r] = Es[r];
            ep.csrOff[r] = off;
            off += Es[r];
        }
    }

    (void)hipMemsetAsync(counts4, 0, 4 * (size_t)N * sizeof(int), stream);

    RelPtrs rp;
    rp.rf[0]   = (const float*)d_in[4];  rp.rf[1]   = (const float*)d_in[5];
    rp.rf[2]   = (const float*)d_in[6];  rp.rf[3]   = (const float*)d_in[7];
    rp.Wrel[0] = (const float*)d_in[10]; rp.Wrel[1] = (const float*)d_in[11];
    rp.Wrel[2] = (const float*)d_in[12]; rp.Wrel[3] = (const float*)d_in[13];
    rp.Wupd[0] = (const float*)d_in[24]; rp.Wupd[1] = (const float*)d_in[26];
    rp.Wupd[2] = (const float*)d_in[28]; rp.Wupd[3] = (const float*)d_in[30];
    rp.bupd[0] = (const float*)d_in[25]; rp.bupd[1] = (const float*)d_in[27];
    rp.bupd[2] = (const float*)d_in[29]; rp.bupd[3] = (const float*)d_in[31];
    rel_k<<<dim3(4), dim3(512), 0, stream>>>(rp, wvec, out + 4 * NP);

    // per-relation weight packs (needs wvec for the score columns)
    const int pair[4] = {1, 0, 3, 2};
    PackArgs pa;
    pa.W1[0] = W_user; pa.W2[0] = Wres_user;
    pa.W1[1] = W_item; pa.W2[1] = Wres_item;
    pa.W1[2] = W_item; pa.W2[2] = Wres_item;
    pa.W1[3] = W_item; pa.W2[3] = Wres_item;
    for (int r = 0; r < 4; ++r) {
        pa.wvA[r] = wvec + (size_t)r * 512;
        pa.wvB[r] = wvec + (size_t)pair[r] * 512;
        pa.Bp[r]  = BpArr[r];
    }
    pack_b_k<<<dim3(33, 4), 256, 0, stream>>>(pa);

    // CSR build
    const int geb = (maxE + 255) / 256;
    const int nbx = (N + 1023) / 1024;
    hist_k<<<dim3(geb, 4), 256, 0, stream>>>(ep, counts4, N);
    blksum_k<<<dim3(nbx, 4), 256, 0, stream>>>(counts4, blksum4, N);
    scanblk_k<<<dim3(4), 1024, 0, stream>>>(blksum4, nbx);
    cursor_k<<<dim3(nbx, 4), 256, 0, stream>>>(counts4, blksum4, cursor4, N);
    scatter_k<<<dim3(geb, 4), 256, 0, stream>>>(ep, cursor4, csr_src, N);

    // operand-swap fused GEMM (pool + resid + el/er), all 4 relations batched
    GemmArgs ga;
    ga.A[0] = feat_iu;  ga.bres[0] = bres_user;
    ga.A[1] = feat_ui;  ga.bres[1] = bres_item;
    ga.A[2] = feat_iir; ga.bres[2] = bres_item;
    ga.A[3] = feat_ii;  ga.bres[3] = bres_item;
    for (int r = 0; r < 4; ++r) {
        ga.Bp[r]    = BpArr[r];
        ga.pool[r]  = pool[r];
        ga.resid[r] = resid[pair[r]];
        ga.elOut[r] = el[r];
        ga.erOut[r] = er[pair[r]];
    }
    const int gb = (N + 63) / 64;
    mfma_gemm_k<<<dim3(gb, 4), 256, 0, stream>>>(ga, N);

    // fused aggregation + gated residual + cross-relation fusion
    NodeArgs na;
    for (int r = 0; r < 4; ++r) {
        na.csr[r]    = csr_src + ep.csrOff[r];
        na.cursor[r] = cursor4 + (size_t)r * N;
        na.counts[r] = counts4 + (size_t)r * N;
        na.el[r]     = el[r];
        na.er[r]     = er[r];
        na.pool[r]   = pool[r];
        na.resid[r]  = resid[r];
    }
    const int nb4 = (N + 3) / 4;
    node_k<<<nb4, 256, 0, stream>>>(na,
                                    (const float*)d_in[14], (const float*)d_in[16],
                                    (const float*)d_in[17],
                                    a_user, a_item, out, N);
}